// Round 1
// baseline (459.137 us; speedup 1.0000x reference)
//
#include <hip/hip_runtime.h>
#include <stdint.h>

typedef unsigned short u16;
typedef __bf16 bf16x8 __attribute__((ext_vector_type(8)));
typedef float f32x4 __attribute__((ext_vector_type(4)));

// ---------- helpers ----------
__device__ __forceinline__ u16 f2b(float f) {
  union { float f; uint32_t u; } v; v.f = f;
  uint32_t r = v.u + 0x7fffu + ((v.u >> 16) & 1u);
  return (u16)(r >> 16);
}
__device__ __forceinline__ float b2f(u16 b) {
  union { float f; uint32_t u; } v; v.u = ((uint32_t)b) << 16;
  return v.f;
}
// async 16B/lane global->LDS (dest = uniform base + lane*16)
__device__ __forceinline__ void g2l16(const void* g, void* l) {
  __builtin_amdgcn_global_load_lds(
      (const __attribute__((address_space(1))) void*)g,
      (__attribute__((address_space(3))) void*)l, 16, 0, 0);
}

#define N_SAMP 128
#define OPAD   224
#define ROWS   (N_SAMP * OPAD)   // 28672

// ---------- K0a: weight repack ----------
// W2[9][128][1024] bf16 ; hp_w0t[256][288] ; gt_w0t[256][288] ; gt_w1t[256][256]
__global__ __launch_bounds__(256) void prep_weights(
    const float* __restrict__ conv_w, const float* __restrict__ hp_w0,
    const float* __restrict__ gt_w0, const float* __restrict__ gt_w1,
    u16* __restrict__ W2, u16* __restrict__ hp_w0t,
    u16* __restrict__ gt_w0t, u16* __restrict__ gt_w1t) {
  int idx = blockIdx.x * 256 + threadIdx.x;
  const int nW2 = 9 * 128 * 1024;        // 1179648
  const int nHP = 256 * 288;             // 73728
  const int nGT0 = 256 * 288;
  const int nGT1 = 256 * 256;
  if (idx < nW2) {
    int s = idx / 131072; int r = idx & 131071;
    int cf = r >> 10; int cin = r & 1023;
    W2[idx] = f2b(conv_w[(cf * 1024 + cin) * 9 + s]);
    return;
  }
  idx -= nW2;
  if (idx < nHP) {
    int nn = idx / 288, kk = idx % 288;
    hp_w0t[nn * 288 + kk] = (kk < 258) ? f2b(hp_w0[kk * 256 + nn]) : (u16)0;
    return;
  }
  idx -= nHP;
  if (idx < nGT0) {
    int nn = idx / 288, kk = idx % 288;
    gt_w0t[nn * 288 + kk] = (kk < 258) ? f2b(gt_w0[kk * 256 + nn]) : (u16)0;
    return;
  }
  idx -= nGT0;
  if (idx < nGT1) {
    int nn = idx >> 8, kk = idx & 255;
    gt_w1t[nn * 256 + kk] = f2b(gt_w1[kk * 256 + nn]);
  }
}

// ---------- K0b: image -> imgT[n][256 sp (16x16 padded grid)][1024 cin] bf16 ----------
__global__ __launch_bounds__(256) void prep_img(const float* __restrict__ image,
                                                u16* __restrict__ imgT) {
  __shared__ float t[64][197];
  int n = blockIdx.x >> 4;
  int cin0 = (blockIdx.x & 15) * 64;
  const float* src = image + ((size_t)n * 1024 + cin0) * 196;
  for (int e = threadIdx.x; e < 64 * 196; e += 256) {
    int c = e / 196, sp = e % 196;
    t[c][sp] = src[c * 196 + sp];
  }
  __syncthreads();
  int w = threadIdx.x >> 6, lane = threadIdx.x & 63;
  for (int i = 0; i < 64; ++i) {
    int spg = i * 4 + w;
    int gy = spg >> 4, gx = spg & 15;
    float v = 0.f;
    if (gy >= 1 && gy <= 14 && gx >= 1 && gx <= 14) v = t[lane][(gy - 1) * 14 + (gx - 1)];
    imgT[(((size_t)(n * 256 + spg)) << 10) + cin0 + lane] = f2b(v);
  }
}

// ---------- K2: qeb cols 128..287 (+ zero padded rows' cols 0..127) ----------
__global__ __launch_bounds__(256) void fill_qe(const float* __restrict__ code,
                                               u16* __restrict__ qeb) {
  int base = blockIdx.x * 8;
  for (int rr = 0; rr < 8; ++rr) {
    int r = base + rr;
    int n = r / 224, o = r % 224;
    int y = o / 14, x = o % 14;
    bool valid = o < 196;
    u16* row = qeb + (size_t)r * 288;
    for (int c = threadIdx.x; c < 288; c += 256) {
      u16 v;
      if (c < 128) { if (valid) continue; v = 0; }
      else if (c == 128) v = valid ? f2b(-1.f + 2.f * y / 13.f) : (u16)0;
      else if (c == 129) v = valid ? f2b(-1.f + 2.f * x / 13.f) : (u16)0;
      else if (c < 258) v = valid ? f2b(code[n * 128 + (c - 130)]) : (u16)0;
      else v = 0;
      row[c] = v;
    }
  }
}

// ---------- K1: conv as implicit GEMM  C[o,cf] ----------
__global__ __launch_bounds__(256) void conv_gemm(
    const u16* __restrict__ imgT, const u16* __restrict__ W2,
    const float* __restrict__ conv_b, u16* __restrict__ qeb) {
  __shared__ __align__(16) u16 lA[112 * 32];
  __shared__ __align__(16) u16 lB[128 * 32];
  int tid = threadIdx.x, lane = tid & 63, w = tid >> 6;
  int wg = blockIdx.x;
  int n = wg >> 1;
  int oBase = (wg & 1) * 112;
  int kb = (lane & 3) * 8;

  int oA0 = oBase + w * 16 + (lane >> 2);
  int oA1 = oBase + (w + 4) * 16 + (lane >> 2);
  int y0 = oA0 / 14, x0 = oA0 % 14; bool v0 = oA0 < 196;
  int y1 = oA1 / 14, x1 = oA1 % 14; bool v1 = oA1 < 196;
  bool has1 = (w < 3);

  int cf0 = w * 16 + (lane >> 2);
  int cf1 = (w + 4) * 16 + (lane >> 2);

  f32x4 acc[7][2];
#pragma unroll
  for (int mt = 0; mt < 7; ++mt)
#pragma unroll
    for (int j = 0; j < 2; ++j) acc[mt][j] = (f32x4){0.f, 0.f, 0.f, 0.f};

  int colW = w * 32;
  for (int s = 0; s < 9; ++s) {
    int dy = s / 3, dx = s % 3;
    int sp0 = v0 ? ((y0 + dy) * 16 + (x0 + dx)) : 0;
    int sp1 = v1 ? ((y1 + dy) * 16 + (x1 + dx)) : 0;
    const u16* gA0 = imgT + (((size_t)(n * 256 + sp0)) << 10) + kb;
    const u16* gA1 = imgT + (((size_t)(n * 256 + sp1)) << 10) + kb;
    const u16* gB0 = W2 + (((size_t)(s * 128 + cf0)) << 10) + kb;
    const u16* gB1 = W2 + (((size_t)(s * 128 + cf1)) << 10) + kb;
    for (int cb = 0; cb < 32; ++cb) {
      __syncthreads();
      g2l16(gA0 + cb * 32, &lA[w * 512]);
      if (has1) g2l16(gA1 + cb * 32, &lA[(w + 4) * 512]);
      g2l16(gB0 + cb * 32, &lB[w * 512]);
      g2l16(gB1 + cb * 32, &lB[(w + 4) * 512]);
      __syncthreads();
      bf16x8 af[7];
#pragma unroll
      for (int mt = 0; mt < 7; ++mt)
        af[mt] = *(const bf16x8*)&lA[(mt * 16 + (lane & 15)) * 32 + (lane >> 4) * 8];
#pragma unroll
      for (int j = 0; j < 2; ++j) {
        bf16x8 bfr = *(const bf16x8*)&lB[(colW + j * 16 + (lane & 15)) * 32 + (lane >> 4) * 8];
#pragma unroll
        for (int mt = 0; mt < 7; ++mt)
          acc[mt][j] = __builtin_amdgcn_mfma_f32_16x16x32_bf16(af[mt], bfr, acc[mt][j], 0, 0, 0);
      }
    }
  }
  int q = lane >> 4, c = lane & 15;
#pragma unroll
  for (int mt = 0; mt < 7; ++mt)
#pragma unroll
    for (int j = 0; j < 2; ++j) {
      int cf = colW + j * 16 + c;
      float bv = conv_b[cf];
#pragma unroll
      for (int r = 0; r < 4; ++r) {
        int o = oBase + mt * 16 + q * 4 + r;
        if (o < 196) qeb[(size_t)(n * 224 + o) * 288 + cf] = f2b(acc[mt][j][r] + bv);
      }
    }
}

// ---------- generic GEMM skeleton: C[28672, 256] = A[28672,KP]bf16 * Bt[256,KP]^T ----------
// MODE 0: h_psi -> att atomics.  MODE 1: g_theta L1 -> g1 store.  MODE 2: g_theta L2 -> relations atomics.
template <int MODE, int KP, int KC>
__global__ __launch_bounds__(256) void gemm_kernel(
    const u16* __restrict__ A, const u16* __restrict__ Bt,
    const float* __restrict__ bias, const float* __restrict__ vec,
    float* __restrict__ outF, u16* __restrict__ outB) {
  __shared__ __align__(16) u16 lA[112 * 32];
  __shared__ __align__(16) u16 lB[128 * 32];
  int tid = threadIdx.x, lane = tid & 63, w = tid >> 6;
  int bx = blockIdx.x, by = blockIdx.y;
  int r0 = bx * 112;
  int cBase = by * 128;
  int kb = (lane & 3) * 8;
  int rA0 = r0 + w * 16 + (lane >> 2);
  int rA1 = r0 + (w + 4) * 16 + (lane >> 2);
  bool has1 = (w < 3);
  const u16* gA0 = A + (size_t)rA0 * KP + kb;
  const u16* gA1 = A + (size_t)rA1 * KP + kb;
  int cB0 = cBase + w * 16 + (lane >> 2);
  int cB1 = cBase + (w + 4) * 16 + (lane >> 2);
  const u16* gB0 = Bt + (size_t)cB0 * KP + kb;
  const u16* gB1 = Bt + (size_t)cB1 * KP + kb;

  f32x4 acc[7][2];
#pragma unroll
  for (int mt = 0; mt < 7; ++mt)
#pragma unroll
    for (int j = 0; j < 2; ++j) acc[mt][j] = (f32x4){0.f, 0.f, 0.f, 0.f};
  int colW = w * 32;

  for (int cb = 0; cb < KC; ++cb) {
    __syncthreads();
    g2l16(gA0 + cb * 32, &lA[w * 512]);
    if (has1) g2l16(gA1 + cb * 32, &lA[(w + 4) * 512]);
    g2l16(gB0 + cb * 32, &lB[w * 512]);
    g2l16(gB1 + cb * 32, &lB[(w + 4) * 512]);
    __syncthreads();
    bf16x8 af[7];
#pragma unroll
    for (int mt = 0; mt < 7; ++mt)
      af[mt] = *(const bf16x8*)&lA[(mt * 16 + (lane & 15)) * 32 + (lane >> 4) * 8];
#pragma unroll
    for (int j = 0; j < 2; ++j) {
      bf16x8 bfr = *(const bf16x8*)&lB[(colW + j * 16 + (lane & 15)) * 32 + (lane >> 4) * 8];
#pragma unroll
      for (int mt = 0; mt < 7; ++mt)
        acc[mt][j] = __builtin_amdgcn_mfma_f32_16x16x32_bf16(af[mt], bfr, acc[mt][j], 0, 0, 0);
    }
  }

  int q = lane >> 4, c = lane & 15;
  if (MODE == 0) {
    float attp[7][4];
#pragma unroll
    for (int mt = 0; mt < 7; ++mt)
#pragma unroll
      for (int r = 0; r < 4; ++r) attp[mt][r] = 0.f;
#pragma unroll
    for (int j = 0; j < 2; ++j) {
      int col = cBase + colW + j * 16 + c;
      float b0 = bias[col], w1 = vec[col];
#pragma unroll
      for (int mt = 0; mt < 7; ++mt)
#pragma unroll
        for (int r = 0; r < 4; ++r) {
          float v = fmaxf(acc[mt][j][r] + b0, 0.f);
          attp[mt][r] += v * w1;
        }
    }
#pragma unroll
    for (int mt = 0; mt < 7; ++mt)
#pragma unroll
      for (int r = 0; r < 4; ++r) {
        float p = attp[mt][r];
        p += __shfl_xor(p, 1, 64);
        p += __shfl_xor(p, 2, 64);
        p += __shfl_xor(p, 4, 64);
        p += __shfl_xor(p, 8, 64);
        if (c == 0) atomicAdd(&outF[r0 + mt * 16 + q * 4 + r], p);
      }
  } else if (MODE == 1) {
    int n = bx >> 1;
#pragma unroll
    for (int mt = 0; mt < 7; ++mt)
#pragma unroll
      for (int j = 0; j < 2; ++j) {
        int col = cBase + colW + j * 16 + c;
        float b = bias[n * 256 + col];
#pragma unroll
        for (int r = 0; r < 4; ++r) {
          int row = r0 + mt * 16 + q * 4 + r;
          outB[(size_t)row * 256 + col] = f2b(fmaxf(acc[mt][j][r] + b, 0.f));
        }
      }
  } else {
    int n = bx >> 1;
    int ob = (bx & 1) * 112;
#pragma unroll
    for (int j = 0; j < 2; ++j) {
      int col = cBase + colW + j * 16 + c;
      float b = bias[col];
      float sum = 0.f;
#pragma unroll
      for (int mt = 0; mt < 7; ++mt)
#pragma unroll
        for (int r = 0; r < 4; ++r) {
          int o = ob + mt * 16 + q * 4 + r;
          if (o < 196) sum += fmaxf(acc[mt][j][r] + b, 0.f);
        }
      sum += __shfl_xor(sum, 16, 64);
      sum += __shfl_xor(sum, 32, 64);
      if (q == 0) atomicAdd(&outF[n * 256 + col], sum);
    }
  }
}

// ---------- K5: softmax over objects, soft-select, per-n bias2 ----------
__global__ __launch_bounds__(256) void sel_kernel(
    const float* __restrict__ att, const u16* __restrict__ qeb,
    const float* __restrict__ gt_w0, const float* __restrict__ gt_b0,
    float* __restrict__ bias2) {
  int n = blockIdx.x, t = threadIdx.x;
  __shared__ float sm[196];
  __shared__ float sel[130];
  __shared__ float red[8];
  float a = (t < 196) ? att[n * 224 + t] : -1e30f;
  float m = a;
  for (int mask = 1; mask < 64; mask <<= 1) m = fmaxf(m, __shfl_xor(m, mask, 64));
  if ((t & 63) == 0) red[t >> 6] = m;
  __syncthreads();
  float M = fmaxf(fmaxf(red[0], red[1]), fmaxf(red[2], red[3]));
  float e = (t < 196) ? expf(a - M) : 0.f;
  float sAcc = e;
  for (int mask = 1; mask < 64; mask <<= 1) sAcc += __shfl_xor(sAcc, mask, 64);
  if ((t & 63) == 0) red[4 + (t >> 6)] = sAcc;
  __syncthreads();
  float S = red[4] + red[5] + red[6] + red[7];
  if (t < 196) sm[t] = e / S;
  __syncthreads();
  if (t < 130) {
    float acc = 0.f;
    const u16* col = qeb + (size_t)n * 224 * 288 + t;
    for (int o = 0; o < 196; ++o) acc += sm[o] * b2f(col[(size_t)o * 288]);
    sel[t] = acc;
  }
  __syncthreads();
  float acc2 = gt_b0[t];
  for (int d = 0; d < 130; ++d) acc2 += sel[d] * gt_w0[(258 + d) * 256 + t];
  bias2[n * 256 + t] = acc2;
}

// ---------- K8: f_phi ----------
__global__ __launch_bounds__(256) void fphi(
    const float* __restrict__ relations, const float* __restrict__ fp_w0,
    const float* __restrict__ fp_b0, const float* __restrict__ fp_w1,
    const float* __restrict__ fp_b1, float* __restrict__ out) {
  int n = blockIdx.x, t = threadIdx.x;
  __shared__ float rel[256];
  __shared__ float f[256];
  rel[t] = relations[n * 256 + t];
  __syncthreads();
  float acc = fp_b0[t];
  for (int k = 0; k < 256; ++k) acc += rel[k] * fp_w0[k * 256 + t];
  f[t] = fmaxf(acc, 0.f);
  __syncthreads();
  if (t < 32) {
    float o = fp_b1[0];
    for (int k = 0; k < 256; ++k) o += f[k] * fp_w1[k * 32 + t];
    out[n * 32 + t] = o;
  }
}

extern "C" void kernel_launch(void* const* d_in, const int* in_sizes, int n_in,
                              void* d_out, int out_size, void* d_ws, size_t ws_size,
                              hipStream_t stream) {
  const float* image = (const float*)d_in[0];
  const float* code = (const float*)d_in[1];
  const float* conv_w = (const float*)d_in[2];
  const float* conv_b = (const float*)d_in[3];
  const float* hp_w0 = (const float*)d_in[4];
  const float* hp_b0 = (const float*)d_in[5];
  const float* hp_w1 = (const float*)d_in[6];
  /* hp_b1 = d_in[7]: softmax shift-invariant, dropped */
  const float* gt_w0 = (const float*)d_in[8];
  const float* gt_b0 = (const float*)d_in[9];
  const float* gt_w1 = (const float*)d_in[10];
  const float* gt_b1 = (const float*)d_in[11];
  const float* fp_w0 = (const float*)d_in[12];
  const float* fp_b0 = (const float*)d_in[13];
  const float* fp_w1 = (const float*)d_in[14];
  const float* fp_b1 = (const float*)d_in[15];
  float* out = (float*)d_out;

  char* p = (char*)d_ws;
  u16* imgT = (u16*)p;   p += (size_t)128 * 256 * 1024 * 2;   // 67.1 MB
  u16* W2 = (u16*)p;     p += (size_t)9 * 128 * 1024 * 2;     // 2.36 MB
  u16* qeb = (u16*)p;    p += (size_t)ROWS * 288 * 2;         // 16.5 MB
  u16* hp_w0t = (u16*)p; p += (size_t)256 * 288 * 2;
  u16* gt_w0t = (u16*)p; p += (size_t)256 * 288 * 2;
  u16* gt_w1t = (u16*)p; p += (size_t)256 * 256 * 2;
  float* att = (float*)p;   p += (size_t)ROWS * 4;
  float* bias2 = (float*)p; p += (size_t)128 * 256 * 4;
  u16* g1 = (u16*)p;        p += (size_t)ROWS * 256 * 2;      // 14.7 MB
  float* relations = (float*)p; p += (size_t)128 * 256 * 4;

  hipMemsetAsync(att, 0, (size_t)ROWS * 4, stream);
  hipMemsetAsync(relations, 0, (size_t)128 * 256 * 4, stream);

  prep_weights<<<5440, 256, 0, stream>>>(conv_w, hp_w0, gt_w0, gt_w1, W2, hp_w0t, gt_w0t, gt_w1t);
  prep_img<<<2048, 256, 0, stream>>>(image, imgT);
  fill_qe<<<ROWS / 8, 256, 0, stream>>>(code, qeb);
  conv_gemm<<<256, 256, 0, stream>>>(imgT, W2, conv_b, qeb);
  gemm_kernel<0, 288, 9><<<dim3(256, 2), 256, 0, stream>>>(qeb, hp_w0t, hp_b0, hp_w1, att, nullptr);
  sel_kernel<<<128, 256, 0, stream>>>(att, qeb, gt_w0, gt_b0, bias2);
  gemm_kernel<1, 288, 9><<<dim3(256, 2), 256, 0, stream>>>(qeb, gt_w0t, bias2, nullptr, nullptr, g1);
  gemm_kernel<2, 256, 8><<<dim3(256, 2), 256, 0, stream>>>(g1, gt_w1t, gt_b1, nullptr, relations, nullptr);
  fphi<<<128, 256, 0, stream>>>(relations, fp_w0, fp_b0, fp_w1, fp_b1, out);
}

// Round 2
// 412.899 us; speedup vs baseline: 1.1120x; 1.1120x over previous
//
#include <hip/hip_runtime.h>
#include <stdint.h>

typedef unsigned short u16;
typedef __bf16 bf16x8 __attribute__((ext_vector_type(8)));
typedef float f32x4 __attribute__((ext_vector_type(4)));

// ---------- helpers ----------
__device__ __forceinline__ u16 f2b(float f) {
  union { float f; uint32_t u; } v; v.f = f;
  uint32_t r = v.u + 0x7fffu + ((v.u >> 16) & 1u);
  return (u16)(r >> 16);
}
__device__ __forceinline__ float b2f(u16 b) {
  union { float f; uint32_t u; } v; v.u = ((uint32_t)b) << 16;
  return v.f;
}
// async 16B/lane global->LDS (dest = uniform base + lane*16)
__device__ __forceinline__ void g2l16(const void* g, void* l) {
  __builtin_amdgcn_global_load_lds(
      (const __attribute__((address_space(1))) void*)g,
      (__attribute__((address_space(3))) void*)l, 16, 0, 0);
}

#define N_SAMP 128
#define OPAD   224
#define ROWS   (N_SAMP * OPAD)   // 28672

// ---------- K0a: weight repack ----------
__global__ __launch_bounds__(256) void prep_weights(
    const float* __restrict__ conv_w, const float* __restrict__ hp_w0,
    const float* __restrict__ gt_w0, const float* __restrict__ gt_w1,
    u16* __restrict__ W2, u16* __restrict__ hp_w0t,
    u16* __restrict__ gt_w0t, u16* __restrict__ gt_w1t) {
  int idx = blockIdx.x * 256 + threadIdx.x;
  const int nW2 = 9 * 128 * 1024;
  const int nHP = 256 * 288;
  const int nGT0 = 256 * 288;
  const int nGT1 = 256 * 256;
  if (idx < nW2) {
    int s = idx / 131072; int r = idx & 131071;
    int cf = r >> 10; int cin = r & 1023;
    W2[idx] = f2b(conv_w[(cf * 1024 + cin) * 9 + s]);
    return;
  }
  idx -= nW2;
  if (idx < nHP) {
    int nn = idx / 288, kk = idx % 288;
    hp_w0t[nn * 288 + kk] = (kk < 258) ? f2b(hp_w0[kk * 256 + nn]) : (u16)0;
    return;
  }
  idx -= nHP;
  if (idx < nGT0) {
    int nn = idx / 288, kk = idx % 288;
    gt_w0t[nn * 288 + kk] = (kk < 258) ? f2b(gt_w0[kk * 256 + nn]) : (u16)0;
    return;
  }
  idx -= nGT0;
  if (idx < nGT1) {
    int nn = idx >> 8, kk = idx & 255;
    gt_w1t[nn * 256 + kk] = f2b(gt_w1[kk * 256 + nn]);
  }
}

// ---------- K0b: image -> imgT[n][256 sp (16x16 zero-bordered)][1024 cin] bf16 ----------
__global__ __launch_bounds__(256) void prep_img(const float* __restrict__ image,
                                                u16* __restrict__ imgT) {
  __shared__ float t[64][197];
  int n = blockIdx.x >> 4;
  int cin0 = (blockIdx.x & 15) * 64;
  const float* src = image + ((size_t)n * 1024 + cin0) * 196;
  for (int e = threadIdx.x; e < 64 * 196; e += 256) {
    int c = e / 196, sp = e % 196;
    t[c][sp] = src[c * 196 + sp];
  }
  __syncthreads();
  int w = threadIdx.x >> 6, lane = threadIdx.x & 63;
  for (int i = 0; i < 64; ++i) {
    int spg = i * 4 + w;
    int gy = spg >> 4, gx = spg & 15;
    float v = 0.f;
    if (gy >= 1 && gy <= 14 && gx >= 1 && gx <= 14) v = t[lane][(gy - 1) * 14 + (gx - 1)];
    imgT[(((size_t)(n * 256 + spg)) << 10) + cin0 + lane] = f2b(v);
  }
}

// ---------- K2: qeb cols 128..287 (+ zero padded rows' cols 0..127) ----------
__global__ __launch_bounds__(256) void fill_qe(const float* __restrict__ code,
                                               u16* __restrict__ qeb) {
  int base = blockIdx.x * 8;
  for (int rr = 0; rr < 8; ++rr) {
    int r = base + rr;
    int n = r / 224, o = r % 224;
    int y = o / 14, x = o % 14;
    bool valid = o < 196;
    u16* row = qeb + (size_t)r * 288;
    for (int c = threadIdx.x; c < 288; c += 256) {
      u16 v;
      if (c < 128) { if (valid) continue; v = 0; }
      else if (c == 128) v = valid ? f2b(-1.f + 2.f * y / 13.f) : (u16)0;
      else if (c == 129) v = valid ? f2b(-1.f + 2.f * x / 13.f) : (u16)0;
      else if (c < 258) v = valid ? f2b(code[n * 128 + (c - 130)]) : (u16)0;
      else v = 0;
      row[c] = v;
    }
  }
}

// ---------- K1: conv as implicit GEMM, split-K x3 ----------
// grid 768 = 8 xcd * (16 ngrp * 2 ohalf * 3 kslice); BK=64; swizzled LDS.
__global__ __launch_bounds__(256) void conv_gemm(
    const u16* __restrict__ imgT, const u16* __restrict__ W2,
    float* __restrict__ convAcc) {
  __shared__ __align__(16) u16 lA[112 * 64];
  __shared__ __align__(16) u16 lB[128 * 64];
  int tid = threadIdx.x, lane = tid & 63, w = tid >> 6;
  int wg = blockIdx.x;
  int xcd = wg & 7, grp = wg >> 3;          // same-n blocks land on same XCD
  int n = ((grp / 6) << 3) | xcd;
  int r6 = grp % 6;
  int oh = r6 / 3, ks = r6 % 3;
  int oBase = oh * 112;
  size_t nBase = (size_t)n << 8;
  int rowIn = lane >> 3;                    // row within 8-row staging instr
  int cA = ((lane & 7) ^ rowIn) << 3;       // XOR-swizzled chunk offset (elems)

  // A-row spatial precompute for staging instrs t = w + 4*ii
  int yxA[4];
  for (int ii = 0; ii < 4; ++ii) {
    int t = w + ii * 4;
    int o = oBase + t * 8 + rowIn;
    bool valid = o < 196;
    int y = o / 14, x = o - y * 14;
    yxA[ii] = valid ? (y * 16 + x) : 0;    // invalid rows read border zeros / garbage; outputs discarded
  }

  f32x4 acc[7][2];
#pragma unroll
  for (int mt = 0; mt < 7; ++mt)
#pragma unroll
    for (int j = 0; j < 2; ++j) acc[mt][j] = (f32x4){0.f, 0.f, 0.f, 0.f};

  int l = lane & 15, q = lane >> 4;
  for (int si = 0; si < 3; ++si) {
    int s = ks * 3 + si;
    int off = (s / 3) * 16 + (s % 3);
    const u16* Ws = W2 + ((size_t)(s * 128) << 10);
    for (int cb = 0; cb < 16; ++cb) {
      int k0 = cb << 6;
      __syncthreads();
      // stage A: 14 instrs (waves 0,1: 4 each; waves 2,3: 3 each)
      g2l16(imgT + ((nBase + (size_t)(yxA[0] + off)) << 10) + k0 + cA, &lA[(w) * 512]);
      g2l16(imgT + ((nBase + (size_t)(yxA[1] + off)) << 10) + k0 + cA, &lA[(w + 4) * 512]);
      g2l16(imgT + ((nBase + (size_t)(yxA[2] + off)) << 10) + k0 + cA, &lA[(w + 8) * 512]);
      if (w < 2)
        g2l16(imgT + ((nBase + (size_t)(yxA[3] + off)) << 10) + k0 + cA, &lA[(w + 12) * 512]);
      // stage B: 16 instrs (4 per wave)
#pragma unroll
      for (int ii = 0; ii < 4; ++ii) {
        int t = w + ii * 4;
        g2l16(Ws + ((size_t)(t * 8 + rowIn) << 10) + k0 + cA, &lB[t * 512]);
      }
      __syncthreads();
#pragma unroll
      for (int kk = 0; kk < 2; ++kk) {
        int co = ((((kk << 2) | q) ^ (l & 7)) << 3);
        bf16x8 af[7];
#pragma unroll
        for (int mt = 0; mt < 7; ++mt)
          af[mt] = *(const bf16x8*)&lA[(mt * 16 + l) * 64 + co];
#pragma unroll
        for (int jj = 0; jj < 2; ++jj) {
          bf16x8 bb = *(const bf16x8*)&lB[(w * 32 + jj * 16 + l) * 64 + co];
#pragma unroll
          for (int mt = 0; mt < 7; ++mt)
            acc[mt][jj] = __builtin_amdgcn_mfma_f32_16x16x32_bf16(af[mt], bb, acc[mt][jj], 0, 0, 0);
        }
      }
    }
  }
  // epilogue: atomic fp32 accumulate of the K-slice partial
#pragma unroll
  for (int mt = 0; mt < 7; ++mt) {
    int o = oBase + mt * 16 + q * 4;
#pragma unroll
    for (int r4 = 0; r4 < 4; ++r4) {
      if (o + r4 < 196) {
        float* dst = convAcc + (size_t)(n * 224 + o + r4) * 128 + w * 32 + l;
        atomicAdd(dst, acc[mt][0][r4]);
        atomicAdd(dst + 16, acc[mt][1][r4]);
      }
    }
  }
}

// ---------- K1b: convAcc + bias -> qeb bf16 cols 0..127 ----------
__global__ __launch_bounds__(256) void conv_fix(
    const float* __restrict__ convAcc, const float* __restrict__ conv_b,
    u16* __restrict__ qeb) {
  int idx = blockIdx.x * 256 + threadIdx.x;   // 128*196*32
  int row196 = idx >> 5;
  int c0 = (idx & 31) << 2;
  int n = row196 / 196, o = row196 - n * 196;
  size_t row = (size_t)(n * 224 + o);
  const float4 v = *(const float4*)(convAcc + (row << 7) + c0);
  const float4 b = *(const float4*)(conv_b + c0);
  ushort4 pk;
  pk.x = f2b(v.x + b.x); pk.y = f2b(v.y + b.y);
  pk.z = f2b(v.z + b.z); pk.w = f2b(v.w + b.w);
  *(ushort4*)(qeb + row * 288 + c0) = pk;
}

// ---------- generic GEMM skeleton: C[28672, 256] = A[28672,KP]bf16 * Bt[256,KP]^T ----------
template <int MODE, int KP, int KC>
__global__ __launch_bounds__(256) void gemm_kernel(
    const u16* __restrict__ A, const u16* __restrict__ Bt,
    const float* __restrict__ bias, const float* __restrict__ vec,
    float* __restrict__ outF, u16* __restrict__ outB) {
  __shared__ __align__(16) u16 lA[112 * 32];
  __shared__ __align__(16) u16 lB[128 * 32];
  int tid = threadIdx.x, lane = tid & 63, w = tid >> 6;
  int bx = blockIdx.x, by = blockIdx.y;
  int r0 = bx * 112;
  int cBase = by * 128;
  int kb = (((lane & 3) ^ ((lane >> 3) & 3)) << 3);   // XOR-swizzled source chunk
  int rA0 = r0 + w * 16 + (lane >> 2);
  int rA1 = r0 + (w + 4) * 16 + (lane >> 2);
  bool has1 = (w < 3);
  const u16* gA0 = A + (size_t)rA0 * KP + kb;
  const u16* gA1 = A + (size_t)rA1 * KP + kb;
  int cB0 = cBase + w * 16 + (lane >> 2);
  int cB1 = cBase + (w + 4) * 16 + (lane >> 2);
  const u16* gB0 = Bt + (size_t)cB0 * KP + kb;
  const u16* gB1 = Bt + (size_t)cB1 * KP + kb;

  f32x4 acc[7][2];
#pragma unroll
  for (int mt = 0; mt < 7; ++mt)
#pragma unroll
    for (int j = 0; j < 2; ++j) acc[mt][j] = (f32x4){0.f, 0.f, 0.f, 0.f};
  int colW = w * 32;
  int l = lane & 15, q = lane >> 4;
  int co = ((q ^ ((l >> 1) & 3)) << 3);

  for (int cb = 0; cb < KC; ++cb) {
    __syncthreads();
    g2l16(gA0 + cb * 32, &lA[w * 512]);
    if (has1) g2l16(gA1 + cb * 32, &lA[(w + 4) * 512]);
    g2l16(gB0 + cb * 32, &lB[w * 512]);
    g2l16(gB1 + cb * 32, &lB[(w + 4) * 512]);
    __syncthreads();
    bf16x8 af[7];
#pragma unroll
    for (int mt = 0; mt < 7; ++mt)
      af[mt] = *(const bf16x8*)&lA[(mt * 16 + l) * 32 + co];
#pragma unroll
    for (int j = 0; j < 2; ++j) {
      bf16x8 bfr = *(const bf16x8*)&lB[(colW + j * 16 + l) * 32 + co];
#pragma unroll
      for (int mt = 0; mt < 7; ++mt)
        acc[mt][j] = __builtin_amdgcn_mfma_f32_16x16x32_bf16(af[mt], bfr, acc[mt][j], 0, 0, 0);
    }
  }

  int q4 = lane >> 4, c = lane & 15;
  if (MODE == 0) {
    float attp[7][4];
#pragma unroll
    for (int mt = 0; mt < 7; ++mt)
#pragma unroll
      for (int r = 0; r < 4; ++r) attp[mt][r] = 0.f;
#pragma unroll
    for (int j = 0; j < 2; ++j) {
      int col = cBase + colW + j * 16 + c;
      float b0 = bias[col], w1 = vec[col];
#pragma unroll
      for (int mt = 0; mt < 7; ++mt)
#pragma unroll
        for (int r = 0; r < 4; ++r) {
          float v = fmaxf(acc[mt][j][r] + b0, 0.f);
          attp[mt][r] += v * w1;
        }
    }
#pragma unroll
    for (int mt = 0; mt < 7; ++mt)
#pragma unroll
      for (int r = 0; r < 4; ++r) {
        float p = attp[mt][r];
        p += __shfl_xor(p, 1, 64);
        p += __shfl_xor(p, 2, 64);
        p += __shfl_xor(p, 4, 64);
        p += __shfl_xor(p, 8, 64);
        if (c == 0) atomicAdd(&outF[r0 + mt * 16 + q4 * 4 + r], p);
      }
  } else if (MODE == 1) {
    int n = bx >> 1;
#pragma unroll
    for (int mt = 0; mt < 7; ++mt)
#pragma unroll
      for (int j = 0; j < 2; ++j) {
        int col = cBase + colW + j * 16 + c;
        float b = bias[n * 256 + col];
#pragma unroll
        for (int r = 0; r < 4; ++r) {
          int row = r0 + mt * 16 + q4 * 4 + r;
          outB[(size_t)row * 256 + col] = f2b(fmaxf(acc[mt][j][r] + b, 0.f));
        }
      }
  } else {
    int n = bx >> 1;
    int ob = (bx & 1) * 112;
#pragma unroll
    for (int j = 0; j < 2; ++j) {
      int col = cBase + colW + j * 16 + c;
      float b = bias[col];
      float sum = 0.f;
#pragma unroll
      for (int mt = 0; mt < 7; ++mt)
#pragma unroll
        for (int r = 0; r < 4; ++r) {
          int o = ob + mt * 16 + q4 * 4 + r;
          if (o < 196) sum += fmaxf(acc[mt][j][r] + b, 0.f);
        }
      sum += __shfl_xor(sum, 16, 64);
      sum += __shfl_xor(sum, 32, 64);
      if (q4 == 0) atomicAdd(&outF[n * 256 + col], sum);
    }
  }
}

// ---------- K5: softmax over objects, soft-select, per-n bias2 ----------
__global__ __launch_bounds__(256) void sel_kernel(
    const float* __restrict__ att, const u16* __restrict__ qeb,
    const float* __restrict__ gt_w0, const float* __restrict__ gt_b0,
    float* __restrict__ bias2) {
  int n = blockIdx.x, t = threadIdx.x;
  int w = t >> 6, lane = t & 63;
  __shared__ u16 sq[196][130];
  __shared__ float sm[196];
  __shared__ float sel[130];
  __shared__ float red[8];
  // cooperative stage of qeb[n, 0:196, 0:130]
  const u16* base = qeb + (size_t)n * 224 * 288;
  for (int o = w; o < 196; o += 4) {
    const u16* rowp = base + (size_t)o * 288;
    for (int c = lane; c < 130; c += 64) sq[o][c] = rowp[c];
  }
  float a = (t < 196) ? att[n * 224 + t] : -1e30f;
  float m = a;
  for (int mask = 1; mask < 64; mask <<= 1) m = fmaxf(m, __shfl_xor(m, mask, 64));
  if (lane == 0) red[w] = m;
  __syncthreads();
  float M = fmaxf(fmaxf(red[0], red[1]), fmaxf(red[2], red[3]));
  float e = (t < 196) ? expf(a - M) : 0.f;
  float sAcc = e;
  for (int mask = 1; mask < 64; mask <<= 1) sAcc += __shfl_xor(sAcc, mask, 64);
  if (lane == 0) red[4 + w] = sAcc;
  __syncthreads();
  float S = red[4] + red[5] + red[6] + red[7];
  if (t < 196) sm[t] = e / S;
  __syncthreads();
  if (t < 130) {
    float acc = 0.f;
    for (int o = 0; o < 196; ++o) acc += sm[o] * b2f(sq[o][t]);
    sel[t] = acc;
  }
  __syncthreads();
  float acc2 = gt_b0[t];
  for (int d = 0; d < 130; ++d) acc2 += sel[d] * gt_w0[(258 + d) * 256 + t];
  bias2[n * 256 + t] = acc2;
}

// ---------- K8: f_phi ----------
__global__ __launch_bounds__(256) void fphi(
    const float* __restrict__ relations, const float* __restrict__ fp_w0,
    const float* __restrict__ fp_b0, const float* __restrict__ fp_w1,
    const float* __restrict__ fp_b1, float* __restrict__ out) {
  int n = blockIdx.x, t = threadIdx.x;
  __shared__ float rel[256];
  __shared__ float f[256];
  rel[t] = relations[n * 256 + t];
  __syncthreads();
  float acc = fp_b0[t];
  for (int k = 0; k < 256; ++k) acc += rel[k] * fp_w0[k * 256 + t];
  f[t] = fmaxf(acc, 0.f);
  __syncthreads();
  if (t < 32) {
    float o = fp_b1[0];
    for (int k = 0; k < 256; ++k) o += f[k] * fp_w1[k * 32 + t];
    out[n * 32 + t] = o;
  }
}

extern "C" void kernel_launch(void* const* d_in, const int* in_sizes, int n_in,
                              void* d_out, int out_size, void* d_ws, size_t ws_size,
                              hipStream_t stream) {
  const float* image = (const float*)d_in[0];
  const float* code = (const float*)d_in[1];
  const float* conv_w = (const float*)d_in[2];
  const float* conv_b = (const float*)d_in[3];
  const float* hp_w0 = (const float*)d_in[4];
  const float* hp_b0 = (const float*)d_in[5];
  const float* hp_w1 = (const float*)d_in[6];
  /* hp_b1: softmax shift-invariant, dropped */
  const float* gt_w0 = (const float*)d_in[8];
  const float* gt_b0 = (const float*)d_in[9];
  const float* gt_w1 = (const float*)d_in[10];
  const float* gt_b1 = (const float*)d_in[11];
  const float* fp_w0 = (const float*)d_in[12];
  const float* fp_b0 = (const float*)d_in[13];
  const float* fp_w1 = (const float*)d_in[14];
  const float* fp_b1 = (const float*)d_in[15];
  float* out = (float*)d_out;

  char* p = (char*)d_ws;
  u16* imgT = (u16*)p;   p += (size_t)128 * 256 * 1024 * 2;   // 67.1 MB
  u16* W2 = (u16*)p;     p += (size_t)9 * 128 * 1024 * 2;     // 2.36 MB
  u16* qeb = (u16*)p;    p += (size_t)ROWS * 288 * 2;         // 16.5 MB
  u16* hp_w0t = (u16*)p; p += (size_t)256 * 288 * 2;
  u16* gt_w0t = (u16*)p; p += (size_t)256 * 288 * 2;
  u16* gt_w1t = (u16*)p; p += (size_t)256 * 256 * 2;
  float* att = (float*)p;   p += (size_t)ROWS * 4;
  float* bias2 = (float*)p; p += (size_t)128 * 256 * 4;
  float* convAcc = (float*)p; p += (size_t)ROWS * 128 * 4;    // 14.7 MB; reused as g1
  float* relations = (float*)p; p += (size_t)128 * 256 * 4;
  u16* g1 = (u16*)convAcc;   // alias: convAcc dead after conv_fix, g1 born at MODE1

  hipMemsetAsync(att, 0, (size_t)ROWS * 4, stream);
  hipMemsetAsync(relations, 0, (size_t)128 * 256 * 4, stream);
  hipMemsetAsync(convAcc, 0, (size_t)ROWS * 128 * 4, stream);

  prep_weights<<<5440, 256, 0, stream>>>(conv_w, hp_w0, gt_w0, gt_w1, W2, hp_w0t, gt_w0t, gt_w1t);
  prep_img<<<2048, 256, 0, stream>>>(image, imgT);
  fill_qe<<<ROWS / 8, 256, 0, stream>>>(code, qeb);
  conv_gemm<<<768, 256, 0, stream>>>(imgT, W2, convAcc);
  conv_fix<<<3136, 256, 0, stream>>>(convAcc, conv_b, qeb);
  gemm_kernel<0, 288, 9><<<dim3(256, 2), 256, 0, stream>>>(qeb, hp_w0t, hp_b0, hp_w1, att, nullptr);
  sel_kernel<<<128, 256, 0, stream>>>(att, qeb, gt_w0, gt_b0, bias2);
  gemm_kernel<1, 288, 9><<<dim3(256, 2), 256, 0, stream>>>(qeb, gt_w0t, bias2, nullptr, nullptr, g1);
  gemm_kernel<2, 256, 8><<<dim3(256, 2), 256, 0, stream>>>(g1, gt_w1t, gt_b1, nullptr, relations, nullptr);
  fphi<<<128, 256, 0, stream>>>(relations, fp_w0, fp_b0, fp_w1, fp_b1, out);
}